// Round 5
// baseline (156.067 us; speedup 1.0000x reference)
//
#include <hip/hip_runtime.h>
#include <hip/hip_bf16.h>

// Problem constants (B=2, M=2048, HS=1024, K=16 heads, D=64)
#define MM   2048
#define HSZ  1024
#define KH   16
#define DH   64

typedef __attribute__((ext_vector_type(8))) short bf16x8;
typedef __attribute__((ext_vector_type(4))) float f32x4;
typedef __attribute__((ext_vector_type(8))) unsigned short u16x8;

#define GLOAD_LDS16(gp, lp) \
    __builtin_amdgcn_global_load_lds( \
        (const __attribute__((address_space(1))) unsigned int*)(gp), \
        (__attribute__((address_space(3))) unsigned int*)(lp), 16, 0, 0)

__device__ __forceinline__ unsigned short f2bf(float x) {
    union { float f; unsigned u; } v; v.f = x;
    unsigned r = v.u + 0x7FFFu + ((v.u >> 16) & 1u);
    return (unsigned short)(r >> 16);
}

// ---------------- weight converts, both in one launch ----------------
__global__ void cvt_w(const float* __restrict__ w0, const float* __restrict__ w1,
                      unsigned short* __restrict__ o0, unsigned short* __restrict__ o1) {
    int bid = blockIdx.x;
    const float* in = (bid < 1024) ? w0 : w1;
    unsigned short* out = (bid < 1024) ? o0 : o1;
    int i = ((bid & 1023) * 256 + threadIdx.x) * 4;
    float4 v = *(const float4*)(in + i);
    ushort4 o;
    o.x = f2bf(v.x); o.y = f2bf(v.y); o.z = f2bf(v.z); o.w = f2bf(v.w);
    *(ushort4*)(out + i) = o;
}

// ---------------- span projection: 8 rows/block, W_span amortized 8x ----------------
__global__ __launch_bounds__(256) void span_proj(
    const float* __restrict__ h, const float* __restrict__ Wspan,
    float* __restrict__ mean_, float* __restrict__ soft_,
    unsigned short* __restrict__ h_bf)
{
    __shared__ float hrow[8][HSZ];
    int row0 = blockIdx.x * 8;
    int t = threadIdx.x;
    #pragma unroll
    for (int i = 0; i < 8; ++i) {
        int li = t + 256 * i;                // float4 id 0..2047
        int r = li >> 8, c4 = (li & 255) * 4;
        float4 hv = *(const float4*)&h[(long)(row0 + r) * HSZ + c4];
        *(float4*)&hrow[r][c4] = hv;
        ushort4 hb;
        hb.x = f2bf(hv.x); hb.y = f2bf(hv.y); hb.z = f2bf(hv.z); hb.w = f2bf(hv.w);
        *(ushort4*)&h_bf[(long)(row0 + r) * HSZ + c4] = hb;
    }
    __syncthreads();
    int o = t >> 3, part = t & 7;            // 32 outputs x 8 partial-lanes
    const float* w = Wspan + o * HSZ;
    float4 acc[8] = {};
    for (int i = 0; i < 32; ++i) {
        int c = part * 4 + i * 32;
        float4 wv = *(const float4*)&w[c];
        #pragma unroll
        for (int r = 0; r < 8; ++r) {
            float4 a = *(const float4*)&hrow[r][c];
            acc[r].x += a.x * wv.x; acc[r].y += a.y * wv.y;
            acc[r].z += a.z * wv.z; acc[r].w += a.w * wv.w;
        }
    }
    #pragma unroll
    for (int r = 0; r < 8; ++r) {
        float s = acc[r].x + acc[r].y + acc[r].z + acc[r].w;
        s += __shfl_xor(s, 1, 64);
        s += __shfl_xor(s, 2, 64);
        s += __shfl_xor(s, 4, 64);
        if (part == 0) {
            int m = row0 + r;
            int b = m >> 11, mm = m & 2047;
            int bk = b * KH + (o >> 1);
            if ((o & 1) == 0) {
                mean_[bk * MM + mm] = (1.f / (1.f + __expf(-s))) * (float)MM;
            } else {
                float sp = (s > 15.f) ? s : log1pf(__expf(s));
                soft_[bk * MM + mm] = sp;
            }
        }
    }
}

// ---------------- deterministic counting sort of rows by mean/64, per (b,head) ----------------
__global__ __launch_bounds__(256) void sort_rows(
    const float* __restrict__ mean_, int* __restrict__ perm)
{
    __shared__ unsigned short hist[32][257];
    __shared__ int binTot[32];
    __shared__ int binStart[32];
    int bk = blockIdx.x, t = threadIdx.x;
    int bins[8];
    #pragma unroll
    for (int i = 0; i < 8; ++i) {
        float mq = mean_[bk * MM + t * 8 + i];
        int b = (int)(mq * (1.f / 64.f));
        bins[i] = min(31, max(0, b));
    }
    for (int b = 0; b < 32; ++b) hist[b][t] = 0;
    __syncthreads();
    #pragma unroll
    for (int i = 0; i < 8; ++i) hist[bins[i]][t]++;   // own column, race-free
    __syncthreads();
    int w = t >> 6, l = t & 63;
    for (int b = w * 8; b < w * 8 + 8; ++b) {
        int carry = 0;
        for (int g = 0; g < 4; ++g) {
            int v = (int)hist[b][g * 64 + l];
            int x = v;
            #pragma unroll
            for (int off = 1; off < 64; off <<= 1) {
                int y = __shfl_up(x, off, 64);
                if (l >= off) x += y;
            }
            hist[b][g * 64 + l] = (unsigned short)(x - v + carry);
            carry += __shfl(x, 63, 64);
        }
        if (l == 0) binTot[b] = carry;
    }
    __syncthreads();
    if (t == 0) {
        int s = 0;
        for (int b = 0; b < 32; ++b) { binStart[b] = s; s += binTot[b]; }
    }
    __syncthreads();
    #pragma unroll
    for (int i = 0; i < 8; ++i) {
        int b = bins[i];
        int prior = 0;
        #pragma unroll
        for (int j = 0; j < 8; ++j) if (j < i && bins[j] == b) prior++;
        int pos = binStart[b] + (int)hist[b][t] + prior;
        perm[bk * MM + pos] = t * 8 + i;
    }
}

// ---------------- bf16 MFMA GEMM: C[i,j] = sum_k A[i,k]*B[j,k] ----------------
// 128(M) x 64(N) tile, BK=64, 256 threads (4 waves 2x2, wave tile 64x32).
// Counted-vmcnt double-buffer pipeline: never drain to 0 in the main loop.
template<int STORE_BF16>
__global__ __launch_bounds__(256) void gemm_bt(
    const unsigned short* __restrict__ A, const unsigned short* __restrict__ Bm,
    void* __restrict__ Cv, int N, int Kd,
    long aZ, long bZ, long cZ)
{
    __shared__ __align__(16) unsigned short As[2][128 * 64];
    __shared__ __align__(16) unsigned short Bs[2][64 * 64];
    const unsigned short* Ab = A  + blockIdx.z * aZ;
    const unsigned short* Bb = Bm + blockIdx.z * bZ;
    long czoff = blockIdx.z * cZ;
    int row0 = blockIdx.y * 128;
    int col0 = blockIdx.x * 64;
    int t = threadIdx.x;
    int wid = t >> 6, l = t & 63;
    int wr = wid >> 1, wc = wid & 1;
    int lr = l & 15, lhi = l >> 4;

    #define SROW(li) ((li) >> 3)
    #define SCOL(li) ((((li) & 7) ^ (SROW(li) & 7)) * 8)
    #define STAGE(buf, k0s) do { \
        int a0 = t, a1 = t + 256, a2 = t + 512, a3 = t + 768; \
        GLOAD_LDS16(Ab + (long)(row0 + SROW(a0)) * Kd + (k0s) + SCOL(a0), &As[buf][a0 * 8]); \
        GLOAD_LDS16(Ab + (long)(row0 + SROW(a1)) * Kd + (k0s) + SCOL(a1), &As[buf][a1 * 8]); \
        GLOAD_LDS16(Ab + (long)(row0 + SROW(a2)) * Kd + (k0s) + SCOL(a2), &As[buf][a2 * 8]); \
        GLOAD_LDS16(Ab + (long)(row0 + SROW(a3)) * Kd + (k0s) + SCOL(a3), &As[buf][a3 * 8]); \
        GLOAD_LDS16(Bb + (long)(col0 + SROW(a0)) * Kd + (k0s) + SCOL(a0), &Bs[buf][a0 * 8]); \
        GLOAD_LDS16(Bb + (long)(col0 + SROW(a1)) * Kd + (k0s) + SCOL(a1), &Bs[buf][a1 * 8]); \
    } while (0)

    f32x4 acc[4][2] = {};
    int nk = Kd >> 6;

    STAGE(0, 0);

    for (int ks = 0; ks < nk; ++ks) {
        int cur = ks & 1;
        if (ks + 1 < nk) {
            STAGE(cur ^ 1, (ks + 1) << 6);
            asm volatile("s_waitcnt vmcnt(6)" ::: "memory");   // tile ks retired, 6 in flight
        } else {
            asm volatile("s_waitcnt vmcnt(0)" ::: "memory");
        }
        __builtin_amdgcn_s_barrier();

        bf16x8 af[2][4], bfr[2][2];
        #pragma unroll
        for (int kk = 0; kk < 2; ++kk) {
            int slotx = ((kk * 4 + lhi) ^ (lr & 7)) << 3;
            #pragma unroll
            for (int i = 0; i < 4; ++i)
                af[kk][i] = *(const bf16x8*)&As[cur][(wr * 64 + i * 16 + lr) * 64 + slotx];
            #pragma unroll
            for (int j = 0; j < 2; ++j)
                bfr[kk][j] = *(const bf16x8*)&Bs[cur][(wc * 32 + j * 16 + lr) * 64 + slotx];
        }
        asm volatile("s_waitcnt lgkmcnt(0)" ::: "memory");
        __builtin_amdgcn_sched_barrier(0);
        __builtin_amdgcn_s_barrier();     // all waves done reading buf cur -> next STAGE may overwrite

        #pragma unroll
        for (int kk = 0; kk < 2; ++kk)
            #pragma unroll
            for (int i = 0; i < 4; ++i)
                #pragma unroll
                for (int j = 0; j < 2; ++j)
                    acc[i][j] = __builtin_amdgcn_mfma_f32_16x16x32_bf16(af[kk][i], bfr[kk][j], acc[i][j], 0, 0, 0);
    }

    // C/D layout: col = l&15, row = (l>>4)*4 + r_
    #pragma unroll
    for (int i = 0; i < 4; ++i) {
        int rbase = row0 + wr * 64 + i * 16 + lhi * 4;
        #pragma unroll
        for (int j = 0; j < 2; ++j) {
            int cidx = col0 + wc * 32 + j * 16 + lr;
            #pragma unroll
            for (int r_ = 0; r_ < 4; ++r_) {
                long idx = czoff + (long)(rbase + r_) * N + cidx;
                if (STORE_BF16) ((unsigned short*)Cv)[idx] = f2bf(acc[i][j][r_]);
                else            ((float*)Cv)[idx] = acc[i][j][r_];
            }
        }
    }
}

// ---------------- fused Gaussian attention over mean-sorted rows ----------------
__global__ __launch_bounds__(512) void attn_gauss(
    const float* __restrict__ mean_, const float* __restrict__ soft_,
    const int* __restrict__ perm,
    const unsigned short* __restrict__ hvT, unsigned short* __restrict__ att)
{
    __shared__ __align__(16) unsigned short Vs[2][64 * 64];
    int flat = blockIdx.x;                   // 0..511
    int swz = (flat & 7) * 64 + (flat >> 3); // XCD-chunked bijection
    int bk = swz >> 4;                       // 0..31
    int qb = swz & 15;                       // 0..15
    int t = threadIdx.x, wid = t >> 6, l = t & 63;
    int b = bk >> 4, head = bk & 15;
    int lr = l & 15, lhi = l >> 4;
    int slot = qb * 128 + wid * 16 + lr;
    int q = perm[bk * MM + slot];
    float mq  = mean_[bk * MM + q];
    float sq  = soft_[bk * MM + q];
    const unsigned short* Vbase = hvT + (long)bk * DH * MM;

    int sr = t >> 3;
    int sc = (((t & 7) ^ (sr & 7)) * 8);

    f32x4 acc[4] = {};
    float lsum = 0.f;
    int jlane0 = lhi * 8;

    GLOAD_LDS16(Vbase + (long)sr * MM + sc, &Vs[0][t * 8]);
    __syncthreads();

    for (int kt = 0; kt < 32; ++kt) {
        int cur = kt & 1;
        int k0 = kt * 64;
        if (kt + 1 < 32)
            GLOAD_LDS16(Vbase + (long)sr * MM + (k0 + 64) + sc, &Vs[cur ^ 1][t * 8]);

        float dmin = fmaxf(fmaxf((float)k0 - mq, mq - (float)(k0 + 63)), 0.f);
        bool active = (sq * dmin * dmin) < 50.f;   // exp(-50) ~ 2e-22
        if (__ballot(active)) {
            #pragma unroll
            for (int kk = 0; kk < 64; kk += 32) {
                bf16x8 pfrag;
                float dbase = (float)(k0 + kk + jlane0) - mq;
                #pragma unroll
                for (int jj = 0; jj < 8; ++jj) {
                    float d_ = dbase + (float)jj;
                    float p = __expf(-sq * d_ * d_);
                    lsum += p;
                    pfrag[jj] = (short)f2bf(p);
                }
                int slotx = (((kk >> 3) + lhi) ^ (lr & 7)) << 3;
                #pragma unroll
                for (int df = 0; df < 4; ++df) {
                    bf16x8 vf = *(const bf16x8*)&Vs[cur][(df * 16 + lr) * 64 + slotx];
                    acc[df] = __builtin_amdgcn_mfma_f32_16x16x32_bf16(pfrag, vf, acc[df], 0, 0, 0);
                }
            }
        }
        __syncthreads();
    }

    lsum += __shfl_xor(lsum, 16, 64);
    lsum += __shfl_xor(lsum, 32, 64);

    int slot_base = qb * 128 + wid * 16;
    #pragma unroll
    for (int r_ = 0; r_ < 4; ++r_) {
        int qr = lhi * 4 + r_;
        float inv = 1.f / __shfl(lsum, qr, 64);
        int qo = perm[bk * MM + slot_base + qr];
        long orow = ((long)b * MM + qo) * HSZ + head * DH;
        #pragma unroll
        for (int df = 0; df < 4; ++df)
            att[orow + df * 16 + lr] = f2bf(acc[df][r_] * inv);
    }
}

extern "C" void kernel_launch(void* const* d_in, const int* in_sizes, int n_in,
                              void* d_out, int out_size, void* d_ws, size_t ws_size,
                              hipStream_t stream) {
    (void)in_sizes; (void)n_in; (void)out_size; (void)ws_size;
    const float* h     = (const float*)d_in[0];   // (2, 2048, 1024)
    const float* Wspan = (const float*)d_in[1];   // (32, 1024)
    const float* Wval  = (const float*)d_in[2];   // (1024, 1024)
    const float* Wout  = (const float*)d_in[3];   // (1024, 1024)
    float* out = (float*)d_out;                   // (2, 2048, 1024) f32

    char* ws = (char*)d_ws;
    unsigned short* h_bf    = (unsigned short*)(ws);               // 8 MB
    unsigned short* Wval_bf = (unsigned short*)(ws +  8388608);    // 2 MB
    unsigned short* Wout_bf = (unsigned short*)(ws + 10485760);    // 2 MB
    unsigned short* hvT     = (unsigned short*)(ws + 12582912);    // 8 MB
    unsigned short* att     = (unsigned short*)(ws + 20971520);    // 8 MB
    float*          mean_   = (float*)(ws + 29360128);             // 256 KB
    float*          soft_   = (float*)(ws + 29622272);             // 256 KB
    int*            perm    = (int*)(ws + 29884416);               // 256 KB

    // ===== MEASUREMENT ROUND: every launch issued TWICE (all kernels are pure
    // functions of their inputs -> bit-identical results; dur decomposes into
    // W_total = dur_R5 - dur_R4, OH = 2*dur_R4 - dur_R5). =====

    cvt_w<<<2048, 256, 0, stream>>>(Wval, Wout, Wval_bf, Wout_bf);
    cvt_w<<<2048, 256, 0, stream>>>(Wval, Wout, Wval_bf, Wout_bf);

    span_proj<<<512, 256, 0, stream>>>(h, Wspan, mean_, soft_, h_bf);
    span_proj<<<512, 256, 0, stream>>>(h, Wspan, mean_, soft_, h_bf);

    sort_rows<<<32, 256, 0, stream>>>(mean_, perm);
    sort_rows<<<32, 256, 0, stream>>>(mean_, perm);

    gemm_bt<1><<<dim3(MM / 64, HSZ / 128, 2), 256, 0, stream>>>(
        Wval_bf, h_bf, hvT, MM, HSZ,
        0L, (long)MM * HSZ, (long)HSZ * MM);
    gemm_bt<1><<<dim3(MM / 64, HSZ / 128, 2), 256, 0, stream>>>(
        Wval_bf, h_bf, hvT, MM, HSZ,
        0L, (long)MM * HSZ, (long)HSZ * MM);

    attn_gauss<<<512, 512, 0, stream>>>(mean_, soft_, perm, hvT, att);
    attn_gauss<<<512, 512, 0, stream>>>(mean_, soft_, perm, hvT, att);

    gemm_bt<0><<<dim3(HSZ / 64, (2 * MM) / 128, 1), 256, 0, stream>>>(
        att, Wout_bf, out, HSZ, HSZ,
        0L, 0L, 0L);
    gemm_bt<0><<<dim3(HSZ / 64, (2 * MM) / 128, 1), 256, 0, stream>>>(
        att, Wout_bf, out, HSZ, HSZ,
        0L, 0L, 0L);
}

// Round 6
// 88.390 us; speedup vs baseline: 1.7657x; 1.7657x over previous
//
#include <hip/hip_runtime.h>
#include <hip/hip_bf16.h>

// Problem constants (B=2, M=2048, HS=1024, K=16 heads, D=64)
#define MM   2048
#define HSZ  1024
#define KH   16
#define DH   64

typedef __attribute__((ext_vector_type(8))) short bf16x8;
typedef __attribute__((ext_vector_type(4))) float f32x4;
typedef __attribute__((ext_vector_type(8))) unsigned short u16x8;

#define GLOAD_LDS16(gp, lp) \
    __builtin_amdgcn_global_load_lds( \
        (const __attribute__((address_space(1))) unsigned int*)(gp), \
        (__attribute__((address_space(3))) unsigned int*)(lp), 16, 0, 0)

__device__ __forceinline__ unsigned short f2bf(float x) {
    union { float f; unsigned u; } v; v.f = x;
    unsigned r = v.u + 0x7FFFu + ((v.u >> 16) & 1u);
    return (unsigned short)(r >> 16);
}

// ---------------- fused: span projection (blocks 0..511) + weight converts (512..2559) ----------------
__global__ __launch_bounds__(256) void span_cvt(
    const float* __restrict__ h, const float* __restrict__ Wspan,
    const float* __restrict__ Wval, const float* __restrict__ Wout,
    float* __restrict__ mean_, float* __restrict__ soft_,
    unsigned short* __restrict__ h_bf,
    unsigned short* __restrict__ Wval_bf, unsigned short* __restrict__ Wout_bf)
{
    __shared__ float hrow[8][HSZ];
    int t = threadIdx.x;

    if (blockIdx.x >= 512) {            // weight convert part
        int bid = blockIdx.x - 512;
        const float* in = (bid < 1024) ? Wval : Wout;
        unsigned short* out = (bid < 1024) ? Wval_bf : Wout_bf;
        int i = ((bid & 1023) * 256 + t) * 4;
        float4 v = *(const float4*)(in + i);
        ushort4 o;
        o.x = f2bf(v.x); o.y = f2bf(v.y); o.z = f2bf(v.z); o.w = f2bf(v.w);
        *(ushort4*)(out + i) = o;
        return;
    }

    // span part: 8 rows per block + fused h f32->bf16 convert
    int row0 = blockIdx.x * 8;
    #pragma unroll
    for (int i = 0; i < 8; ++i) {
        int li = t + 256 * i;                // float4 id 0..2047
        int r = li >> 8, c4 = (li & 255) * 4;
        float4 hv = *(const float4*)&h[(long)(row0 + r) * HSZ + c4];
        *(float4*)&hrow[r][c4] = hv;
        ushort4 hb;
        hb.x = f2bf(hv.x); hb.y = f2bf(hv.y); hb.z = f2bf(hv.z); hb.w = f2bf(hv.w);
        *(ushort4*)&h_bf[(long)(row0 + r) * HSZ + c4] = hb;
    }
    __syncthreads();
    int o = t >> 3, part = t & 7;            // 32 outputs x 8 partial-lanes
    const float* w = Wspan + o * HSZ;
    float4 acc[8] = {};
    for (int i = 0; i < 32; ++i) {
        int c = part * 4 + i * 32;
        float4 wv = *(const float4*)&w[c];
        #pragma unroll
        for (int r = 0; r < 8; ++r) {
            float4 a = *(const float4*)&hrow[r][c];
            acc[r].x += a.x * wv.x; acc[r].y += a.y * wv.y;
            acc[r].z += a.z * wv.z; acc[r].w += a.w * wv.w;
        }
    }
    #pragma unroll
    for (int r = 0; r < 8; ++r) {
        float s = acc[r].x + acc[r].y + acc[r].z + acc[r].w;
        s += __shfl_xor(s, 1, 64);
        s += __shfl_xor(s, 2, 64);
        s += __shfl_xor(s, 4, 64);
        if (part == 0) {
            int m = row0 + r;
            int b = m >> 11, mm = m & 2047;
            int bk = b * KH + (o >> 1);
            if ((o & 1) == 0) {
                mean_[bk * MM + mm] = (1.f / (1.f + __expf(-s))) * (float)MM;
            } else {
                float sp = (s > 15.f) ? s : log1pf(__expf(s));
                soft_[bk * MM + mm] = sp;
            }
        }
    }
}

// ---------------- deterministic counting sort of rows by mean/64, per (b,head) ----------------
__global__ __launch_bounds__(256) void sort_rows(
    const float* __restrict__ mean_, int* __restrict__ perm)
{
    __shared__ unsigned short hist[32][257];
    __shared__ int binTot[32];
    __shared__ int binStart[32];
    int bk = blockIdx.x, t = threadIdx.x;
    int bins[8];
    #pragma unroll
    for (int i = 0; i < 8; ++i) {
        float mq = mean_[bk * MM + t * 8 + i];
        int b = (int)(mq * (1.f / 64.f));
        bins[i] = min(31, max(0, b));
    }
    for (int b = 0; b < 32; ++b) hist[b][t] = 0;
    __syncthreads();
    #pragma unroll
    for (int i = 0; i < 8; ++i) hist[bins[i]][t]++;   // own column, race-free
    __syncthreads();
    int w = t >> 6, l = t & 63;
    for (int b = w * 8; b < w * 8 + 8; ++b) {
        int carry = 0;
        for (int g = 0; g < 4; ++g) {
            int v = (int)hist[b][g * 64 + l];
            int x = v;
            #pragma unroll
            for (int off = 1; off < 64; off <<= 1) {
                int y = __shfl_up(x, off, 64);
                if (l >= off) x += y;
            }
            hist[b][g * 64 + l] = (unsigned short)(x - v + carry);
            carry += __shfl(x, 63, 64);
        }
        if (l == 0) binTot[b] = carry;
    }
    __syncthreads();
    if (t == 0) {
        int s = 0;
        for (int b = 0; b < 32; ++b) { binStart[b] = s; s += binTot[b]; }
    }
    __syncthreads();
    #pragma unroll
    for (int i = 0; i < 8; ++i) {
        int b = bins[i];
        int prior = 0;
        #pragma unroll
        for (int j = 0; j < 8; ++j) if (j < i && bins[j] == b) prior++;
        int pos = binStart[b] + (int)hist[b][t] + prior;
        perm[bk * MM + pos] = t * 8 + i;
    }
}

// ---------------- bf16 MFMA GEMM: C[i,j] = sum_k A[i,k]*B[j,k] ----------------
// 128(M rows) x 64(N cols) tile, BK=32, 256 threads (4 waves 2x2, wave 64x32 out).
// 4 LDS buffers, 3 tiles in flight, ONE barrier per K-step, counted vmcnt ladder.
// XCD-chunked flat-grid swizzle; INNER_Y picks tile-decode order for L2 locality.
template<int STORE_BF16, int INNER_Y>
__global__ __launch_bounds__(256) void gemm_bt(
    const unsigned short* __restrict__ A, const unsigned short* __restrict__ Bm,
    void* __restrict__ Cv, int N, int Kd, int ntx, int nty,
    long aZ, long bZ, long cZ)
{
    __shared__ __align__(16) unsigned short As[4][128 * 32];   // 32 KB
    __shared__ __align__(16) unsigned short Bs[4][64 * 32];    // 16 KB

    // XCD-chunked bijection (512 blocks, 512%8==0): XCD n gets tiles [n*64,(n+1)*64)
    int flat = blockIdx.x;
    int swz = (flat & 7) * 64 + (flat >> 3);
    int bx, by, bz;
    if (INNER_Y) { by = swz % nty; int r = swz / nty; bx = r % ntx; bz = r / ntx; }
    else         { bx = swz % ntx; int r = swz / ntx; by = r % nty; bz = r / nty; }

    const unsigned short* Ab = A  + bz * aZ;
    const unsigned short* Bb = Bm + bz * bZ;
    long czoff = bz * cZ;
    int row0 = by * 128;
    int col0 = bx * 64;
    int t = threadIdx.x;
    int wid = t >> 6, l = t & 63;
    int wr = wid >> 1, wc = wid & 1;
    int lr = l & 15, lhi = l >> 4;

    // staging: A 512 chunks (2/thread), B 256 chunks (1/thread).
    // row r's LDS chunk c holds global k-chunk c ^ ((r>>1)&3)  (2-way-free bank pattern)
    #define STAGE(buf, k0s) do { \
        int aA0 = t, aA1 = t + 256; \
        int rA0 = aA0 >> 2, rA1 = aA1 >> 2, rB0 = t >> 2; \
        int cA0 = (((aA0 & 3) ^ ((rA0 >> 1) & 3)) * 8); \
        int cA1 = (((aA1 & 3) ^ ((rA1 >> 1) & 3)) * 8); \
        int cB0 = (((t   & 3) ^ ((rB0 >> 1) & 3)) * 8); \
        GLOAD_LDS16(Ab + (long)(row0 + rA0) * Kd + (k0s) + cA0, &As[buf][aA0 * 8]); \
        GLOAD_LDS16(Ab + (long)(row0 + rA1) * Kd + (k0s) + cA1, &As[buf][aA1 * 8]); \
        GLOAD_LDS16(Bb + (long)(col0 + rB0) * Kd + (k0s) + cB0, &Bs[buf][t * 8]); \
    } while (0)

    f32x4 acc[4][2] = {};
    int nk = Kd >> 5;                  // BK=32
    int slotA = (lhi ^ ((lr >> 1) & 3)) * 8;

    STAGE(0, 0);
    STAGE(1, 32);
    STAGE(2, 64);

    for (int ks = 0; ks < nk; ++ks) {
        int cur = ks & 3;
        // drain tile ks (3 loads): outstanding before barrier = tiles ks..min(ks+2,nk-1)
        if (ks + 2 < nk)      asm volatile("s_waitcnt vmcnt(6)" ::: "memory");
        else if (ks + 1 < nk) asm volatile("s_waitcnt vmcnt(3)" ::: "memory");
        else                  asm volatile("s_waitcnt vmcnt(0)" ::: "memory");
        __builtin_amdgcn_s_barrier();
        // safe to overwrite buf (ks+3)&3 == buf (ks-1)&3: its reads finished before this barrier
        if (ks + 3 < nk) STAGE((ks + 3) & 3, (ks + 3) << 5);

        bf16x8 af[4], bfr[2];
        #pragma unroll
        for (int i = 0; i < 4; ++i)
            af[i] = *(const bf16x8*)&As[cur][(wr * 64 + i * 16 + lr) * 32 + slotA];
        #pragma unroll
        for (int j = 0; j < 2; ++j)
            bfr[j] = *(const bf16x8*)&Bs[cur][(wc * 32 + j * 16 + lr) * 32 + slotA];
        asm volatile("s_waitcnt lgkmcnt(0)" ::: "memory");
        __builtin_amdgcn_sched_barrier(0);

        #pragma unroll
        for (int i = 0; i < 4; ++i)
            #pragma unroll
            for (int j = 0; j < 2; ++j)
                acc[i][j] = __builtin_amdgcn_mfma_f32_16x16x32_bf16(af[i], bfr[j], acc[i][j], 0, 0, 0);
    }
    #undef STAGE

    // C/D layout: col = l&15, row = (l>>4)*4 + r_
    #pragma unroll
    for (int i = 0; i < 4; ++i) {
        int rbase = row0 + wr * 64 + i * 16 + lhi * 4;
        #pragma unroll
        for (int j = 0; j < 2; ++j) {
            int cidx = col0 + wc * 32 + j * 16 + lr;
            #pragma unroll
            for (int r_ = 0; r_ < 4; ++r_) {
                long idx = czoff + (long)(rbase + r_) * N + cidx;
                if (STORE_BF16) ((unsigned short*)Cv)[idx] = f2bf(acc[i][j][r_]);
                else            ((float*)Cv)[idx] = acc[i][j][r_];
            }
        }
    }
}

// ---------------- fused Gaussian attention over mean-sorted rows ----------------
__global__ __launch_bounds__(512) void attn_gauss(
    const float* __restrict__ mean_, const float* __restrict__ soft_,
    const int* __restrict__ perm,
    const unsigned short* __restrict__ hvT, unsigned short* __restrict__ att)
{
    __shared__ __align__(16) unsigned short Vs[2][64 * 64];
    int flat = blockIdx.x;                   // 0..511
    int swz = (flat & 7) * 64 + (flat >> 3); // XCD-chunked bijection
    int bk = swz >> 4;                       // 0..31
    int qb = swz & 15;                       // 0..15
    int t = threadIdx.x, wid = t >> 6, l = t & 63;
    int b = bk >> 4, head = bk & 15;
    int lr = l & 15, lhi = l >> 4;
    int slot = qb * 128 + wid * 16 + lr;
    int q = perm[bk * MM + slot];
    float mq  = mean_[bk * MM + q];
    float sq  = soft_[bk * MM + q];
    const unsigned short* Vbase = hvT + (long)bk * DH * MM;

    int sr = t >> 3;
    int sc = (((t & 7) ^ (sr & 7)) * 8);

    f32x4 acc[4] = {};
    float lsum = 0.f;
    int jlane0 = lhi * 8;

    GLOAD_LDS16(Vbase + (long)sr * MM + sc, &Vs[0][t * 8]);
    __syncthreads();

    for (int kt = 0; kt < 32; ++kt) {
        int cur = kt & 1;
        int k0 = kt * 64;
        if (kt + 1 < 32)
            GLOAD_LDS16(Vbase + (long)sr * MM + (k0 + 64) + sc, &Vs[cur ^ 1][t * 8]);

        float dmin = fmaxf(fmaxf((float)k0 - mq, mq - (float)(k0 + 63)), 0.f);
        bool active = (sq * dmin * dmin) < 50.f;   // exp(-50) ~ 2e-22
        if (__ballot(active)) {
            #pragma unroll
            for (int kk = 0; kk < 64; kk += 32) {
                bf16x8 pfrag;
                float dbase = (float)(k0 + kk + jlane0) - mq;
                #pragma unroll
                for (int jj = 0; jj < 8; ++jj) {
                    float d_ = dbase + (float)jj;
                    float p = __expf(-sq * d_ * d_);
                    lsum += p;
                    pfrag[jj] = (short)f2bf(p);
                }
                int slotx = (((kk >> 3) + lhi) ^ (lr & 7)) << 3;
                #pragma unroll
                for (int df = 0; df < 4; ++df) {
                    bf16x8 vf = *(const bf16x8*)&Vs[cur][(df * 16 + lr) * 64 + slotx];
                    acc[df] = __builtin_amdgcn_mfma_f32_16x16x32_bf16(pfrag, vf, acc[df], 0, 0, 0);
                }
            }
        }
        __syncthreads();
    }

    lsum += __shfl_xor(lsum, 16, 64);
    lsum += __shfl_xor(lsum, 32, 64);

    int slot_base = qb * 128 + wid * 16;
    #pragma unroll
    for (int r_ = 0; r_ < 4; ++r_) {
        int qr = lhi * 4 + r_;
        float inv = 1.f / __shfl(lsum, qr, 64);
        int qo = perm[bk * MM + slot_base + qr];
        long orow = ((long)b * MM + qo) * HSZ + head * DH;
        #pragma unroll
        for (int df = 0; df < 4; ++df)
            att[orow + df * 16 + lr] = f2bf(acc[df][r_] * inv);
    }
}

extern "C" void kernel_launch(void* const* d_in, const int* in_sizes, int n_in,
                              void* d_out, int out_size, void* d_ws, size_t ws_size,
                              hipStream_t stream) {
    (void)in_sizes; (void)n_in; (void)out_size; (void)ws_size;
    const float* h     = (const float*)d_in[0];   // (2, 2048, 1024)
    const float* Wspan = (const float*)d_in[1];   // (32, 1024)
    const float* Wval  = (const float*)d_in[2];   // (1024, 1024)
    const float* Wout  = (const float*)d_in[3];   // (1024, 1024)
    float* out = (float*)d_out;                   // (2, 2048, 1024) f32

    char* ws = (char*)d_ws;
    unsigned short* h_bf    = (unsigned short*)(ws);               // 8 MB
    unsigned short* Wval_bf = (unsigned short*)(ws +  8388608);    // 2 MB
    unsigned short* Wout_bf = (unsigned short*)(ws + 10485760);    // 2 MB
    unsigned short* hvT     = (unsigned short*)(ws + 12582912);    // 8 MB
    unsigned short* att     = (unsigned short*)(ws + 20971520);    // 8 MB
    float*          mean_   = (float*)(ws + 29360128);             // 256 KB
    float*          soft_   = (float*)(ws + 29622272);             // 256 KB
    int*            perm    = (int*)(ws + 29884416);               // 256 KB

    // span params + h convert + weight converts, one launch
    span_cvt<<<2560, 256, 0, stream>>>(h, Wspan, Wval, Wout,
                                       mean_, soft_, h_bf, Wval_bf, Wout_bf);

    sort_rows<<<32, 256, 0, stream>>>(mean_, perm);

    // value GEMM: hvT[b*1024 + n][m] = sum_c Wval[n,c] * h[b,m,c]
    // tiles: x = m-cols (2048/64=32), y = n-rows (1024/128=8), z = 2; INNER_Y=1
    gemm_bt<1, 1><<<512, 256, 0, stream>>>(
        Wval_bf, h_bf, hvT, MM, HSZ, 32, 8,
        0L, (long)MM * HSZ, (long)HSZ * MM);

    // fused Gaussian attention -> att (B, M, HS) bf16
    attn_gauss<<<512, 512, 0, stream>>>(mean_, soft_, perm, hvT, att);

    // output GEMM: out[b*2048+m][n] = sum_c att[b,m,c] * Wout[n,c]
    // tiles: x = n-cols (1024/64=16), y = m-rows (4096/128=32), z = 1; INNER_Y=0
    gemm_bt<0, 0><<<512, 256, 0, stream>>>(
        att, Wout_bf, out, HSZ, HSZ, 16, 32,
        0L, 0L, 0L);
}